// Round 12
// baseline (206.782 us; speedup 1.0000x reference)
//
#include <hip/hip_runtime.h>

// Problem constants
#define B_DIM 32
#define V_DIM 21
#define D_DIM 512
#define P_DIM 64
#define M_TOTAL 672          // B*V
#define K_TOTAL 32768        // D*P
#define OUT_DIM 96
#define E_DIM 8
#define R_DIM 8
#define H_DIM 256
#define N_TOTAL 160          // OUT_DIM + E*R
#define SCALING 2.0f
#define POOL_SCALE (1.0f / (V_DIM * (float)P_DIM))

// GEMM tiling: coalesced LDS staging, small tiles for residency.
#define BM 64
#define BK 64
#define KSPLIT 64
#define K_PER_SPLIT (K_TOTAL / KSPLIT)   // 512
#define CHUNKS (K_PER_SPLIT / BK)        // 8
#define LDS_K (BK + 8)                   // 72 shorts/row: row stride 144B -> 4-bank rotate
#define LDS_RED_S 20                     // pooled-scratch row stride (floats): 80B, 16B-aligned
#define SMN (M_TOTAL * N_TOTAL)          // 107520 = S matrix (fp32, 430KB, L2-resident)
#define RC_ROWS 4                        // rows per combine block

typedef __attribute__((ext_vector_type(4))) float floatx4;
typedef __attribute__((ext_vector_type(8))) short short8;
typedef __attribute__((ext_vector_type(4))) short shortx4;  // 'short4' is a HIP builtin

__device__ __forceinline__ unsigned short f2bf(float f) {
  union { float f; unsigned int u; } v; v.f = f;
  unsigned int u = v.u + (0x7FFFu + ((v.u >> 16) & 1u));  // RNE
  return (unsigned short)(u >> 16);
}

// ------- convW: [W_base|lora_A] fp32 -> bf16 Wb[160][32768]; zero pooled + S
__global__ __launch_bounds__(256)
void convW_kernel(const float* __restrict__ W_base, const float* __restrict__ lora_A,
                  short* __restrict__ Wb, float* __restrict__ pooled,
                  float* __restrict__ S) {
  int gid = blockIdx.x * 256 + threadIdx.x;
  if (blockIdx.x < 64) pooled[gid] = 0.0f;   // 16384 floats zeroed
  else if (blockIdx.x < 484) {               // 420*256 = 107520 = SMN exactly
    S[(blockIdx.x - 64) * 256 + threadIdx.x] = 0.0f;
  }
  size_t base = (size_t)gid * 8;
  int row = (int)(base >> 15);
  int k = (int)(base & 32767);
  const float* src = (row < OUT_DIM) ? (W_base + ((size_t)row << 15) + k)
                                     : (lora_A + ((size_t)(row - OUT_DIM) << 15) + k);
  floatx4 v0 = ((const floatx4*)src)[0];
  floatx4 v1 = ((const floatx4*)src)[1];
  short8 sv;
  sv[0] = (short)f2bf(v0[0]); sv[1] = (short)f2bf(v0[1]);
  sv[2] = (short)f2bf(v0[2]); sv[3] = (short)f2bf(v0[3]);
  sv[4] = (short)f2bf(v1[0]); sv[5] = (short)f2bf(v1[1]);
  sv[6] = (short)f2bf(v1[2]); sv[7] = (short)f2bf(v1[3]);
  *(short8*)(Wb + base) = sv;
}

// ------- gemm: S[m][n] += x-chunk @ Wb^T (cross-block atomic accumulate into
// the L2-resident 430KB S matrix -- replaces the 27.5MB P-plane round trip).
// A,B staged via LDS (coalesced); pooling v2 (lds_red linear partials).
// 4 blocks/CU resident.
__global__ __launch_bounds__(256, 4)
void gemm_kernel(const float* __restrict__ x, const short* __restrict__ Wb,
                 float* __restrict__ S, float* __restrict__ pooled) {
  __shared__ short ldsA[BM * LDS_K];      //  9,216 B
  __shared__ short ldsB[N_TOTAL * LDS_K]; // 23,040 B
  __shared__ float lds_pool[5 * 8];       // [b_local][d_local = chunk]
  __shared__ __attribute__((aligned(16))) float lds_red[BM * LDS_RED_S]; // 5,120 B
  const int tid = threadIdx.x;
  const int m0 = blockIdx.x * BM;
  const int ky = blockIdx.y;
  const int kbase = ky * K_PER_SPLIT;
  const int lane = tid & 63;
  const int wave = tid >> 6;
  const int quad = lane >> 4;
  const int l16 = lane & 15;
  const int b_first = m0 / V_DIM;
  const int d_first = kbase >> 6;         // k = d*64 + p; one chunk == one d

  if (tid < 40) lds_pool[tid] = 0.0f;

  floatx4 acc[10];                        // wave: rows [wave*16,+16), all 160 n
  #pragma unroll
  for (int nt = 0; nt < 10; ++nt) acc[nt] = (floatx4)(0.0f);

  // staging coords: A: idx=it*256+tid -> arow=idx>>4, u=idx&15 (float4 units;
  // 16-thread group = one row = one d). B: brow=idx>>3, g=idx&7 (short8 units).
  floatx4 pa[4];
  short8 pb[5];

#define ISSUE(c)                                                                \
  {                                                                             \
    const int kc = kbase + (c) * BK;                                            \
    _Pragma("unroll")                                                           \
    for (int it = 0; it < 4; ++it) {                                            \
      int idx = it * 256 + tid;                                                 \
      int arow = idx >> 4;                                                      \
      int u = idx & 15;                                                         \
      int m = m0 + arow;                                                        \
      pa[it] = (m < M_TOTAL)                                                    \
          ? *(const floatx4*)(x + (size_t)m * K_TOTAL + kc + u * 4)             \
          : (floatx4)(0.0f);                                                    \
    }                                                                           \
    _Pragma("unroll")                                                           \
    for (int it = 0; it < 5; ++it) {                                            \
      int idx = it * 256 + tid;                                                 \
      int brow = idx >> 3;                                                      \
      int g = idx & 7;                                                          \
      pb[it] = *(const short8*)(Wb + (size_t)brow * K_TOTAL + kc + g * 8);      \
    }                                                                           \
  }

#define CONVERT_WRITE(c)                                                        \
  {                                                                             \
    _Pragma("unroll")                                                           \
    for (int it = 0; it < 4; ++it) {                                            \
      int idx = it * 256 + tid;                                                 \
      int arow = idx >> 4;                                                      \
      int u = idx & 15;                                                         \
      floatx4 v = pa[it];                                                       \
      /* pooling partial: one scalar per (row, u-slot); linear, conflict-free */\
      lds_red[arow * LDS_RED_S + u] = (v[0] + v[1]) + (v[2] + v[3]);            \
      shortx4 sv;                                                               \
      sv[0] = (short)f2bf(v[0]); sv[1] = (short)f2bf(v[1]);                     \
      sv[2] = (short)f2bf(v[2]); sv[3] = (short)f2bf(v[3]);                     \
      *(shortx4*)&ldsA[arow * LDS_K + u * 4] = sv;                              \
    }                                                                           \
    _Pragma("unroll")                                                           \
    for (int it = 0; it < 5; ++it) {                                            \
      int idx = it * 256 + tid;                                                 \
      int brow = idx >> 3;                                                      \
      int g = idx & 7;                                                          \
      *(short8*)&ldsB[brow * LDS_K + g * 8] = pb[it];                           \
    }                                                                           \
  }

  ISSUE(0);
  __syncthreads();          // lds_pool zeros visible before first atomicAdd
  CONVERT_WRITE(0);

  for (int c = 0; c < CHUNKS; ++c) {
    __syncthreads();        // LDS tiles + lds_red for chunk c ready
    if (c + 1 < CHUNKS) ISSUE(c + 1);     // next chunk's loads fly under MFMA
    #pragma unroll
    for (int ks = 0; ks < 2; ++ks) {
      const int ko = ks * 32 + quad * 8;
      short8 a = *(const short8*)&ldsA[(wave * 16 + l16) * LDS_K + ko];
      #pragma unroll
      for (int nt = 0; nt < 10; ++nt) {
        short8 b = *(const short8*)&ldsB[(nt * 16 + l16) * LDS_K + ko];
        acc[nt] = __builtin_amdgcn_mfma_f32_16x16x32_bf16(a, b, acc[nt], 0, 0, 0);
      }
    }
    // row-sum of lds_red (chunk c = d_first + c): 64 threads, 16 per wave.
    if (quad == 0) {
      int r = wave * 16 + l16;
      const floatx4* rr = (const floatx4*)&lds_red[r * LDS_RED_S];
      floatx4 t0 = rr[0], t1 = rr[1], t2 = rr[2], t3 = rr[3];
      floatx4 tt = (t0 + t1) + (t2 + t3);
      float s = (tt[0] + tt[1]) + (tt[2] + tt[3]);
      int m = m0 + r;
      if (m < M_TOTAL)
        atomicAdd(&lds_pool[(m / V_DIM - b_first) * 8 + c], s);
    }
    __syncthreads();        // all LDS reads of chunk c done
    if (c + 1 < CHUNKS) CONVERT_WRITE(c + 1);
  }

  // S accumulate (D layout: col=lane&15, row=quad*4+reg): atomic adds into
  // the shared 430KB S matrix; L2-resident RMW, fire-and-forget.
  {
    const int mrow = m0 + wave * 16 + quad * 4;
    float* Sp = S + (size_t)mrow * N_TOTAL + l16;
    #pragma unroll
    for (int r = 0; r < 4; ++r)
      if (mrow + r < M_TOTAL)
        #pragma unroll
        for (int nt = 0; nt < 10; ++nt)
          atomicAdd(&Sp[(size_t)r * N_TOTAL + nt * 16], acc[nt][r]);
  }

  // pooled partials -> global (40 atomics/block)
  if (tid < 40) {
    int b = b_first + (tid >> 3);
    int d = d_first + (tid & 7);
    if (b < B_DIM)
      atomicAdd(&pooled[b * D_DIM + d], lds_pool[tid] * POOL_SCALE);
  }
}

// ---------------- router: MLP + softmax + top-2 ------------------------------
__global__ __launch_bounds__(256)
void router_kernel(const float* __restrict__ pooled, const float* __restrict__ W1,
                   const float* __restrict__ b1, const float* __restrict__ W2,
                   const float* __restrict__ b2, float* __restrict__ wfull,
                   float* __restrict__ probs_out) {
  __shared__ float sp[D_DIM];
  __shared__ float sh[H_DIM];
  __shared__ float slog[E_DIM];
  const int b = blockIdx.x;
  const int t = threadIdx.x;
  sp[t] = pooled[b * D_DIM + t];
  sp[t + 256] = pooled[b * D_DIM + t + 256];
  __syncthreads();
  float acc = b1[t];
  const float* w1r = W1 + (size_t)t * D_DIM;
  for (int d = 0; d < D_DIM; ++d) acc += sp[d] * w1r[d];
  sh[t] = fmaxf(acc, 0.0f);
  __syncthreads();
  if (t < E_DIM) {
    float a = b2[t];
    const float* w2r = W2 + t * H_DIM;
    for (int j = 0; j < H_DIM; ++j) a += sh[j] * w2r[j];
    slog[t] = a;
  }
  __syncthreads();
  if (t == 0) {
    float p[E_DIM];
    float mx = slog[0];
    for (int e = 1; e < E_DIM; ++e) mx = fmaxf(mx, slog[e]);
    float se = 0.0f;
    for (int e = 0; e < E_DIM; ++e) { p[e] = __expf(slog[e] - mx); se += p[e]; }
    float inv = 1.0f / se;
    for (int e = 0; e < E_DIM; ++e) { p[e] *= inv; probs_out[b * E_DIM + e] = p[e]; }
    // top-2, lowest index wins ties (strict > keeps earlier index)
    int i0 = 0;
    for (int e = 1; e < E_DIM; ++e) if (p[e] > p[i0]) i0 = e;
    int i1 = (i0 == 0) ? 1 : 0;
    for (int e = 0; e < E_DIM; ++e) if (e != i0 && p[e] > p[i1]) i1 = e;
    float s2 = p[i0] + p[i1];
    float invs = 1.0f / fmaxf(s2, 1e-6f);
    for (int e = 0; e < E_DIM; ++e) {
      float w = 0.0f;
      if (e == i0) w += p[i0] * invs;
      if (e == i1) w += p[i1] * invs;
      wfull[b * E_DIM + e] = w;
    }
  }
}

// ------- combine: out = S_b + b_base + 2*Σ w·(S_l·B); S already summed
__global__ __launch_bounds__(256)
void combine_kernel(const float* __restrict__ S, const float* __restrict__ b_base,
                    const float* __restrict__ lora_B, const float* __restrict__ wfull,
                    float* __restrict__ out) {
  __shared__ float sS[RC_ROWS * N_TOTAL];   // 640 floats
  const int t = threadIdx.x;
  const int NF4 = RC_ROWS * N_TOTAL / 4;    // 160 float4 per block
  if (t < NF4) {
    ((floatx4*)sS)[t] = ((const floatx4*)(S + (size_t)blockIdx.x * RC_ROWS * N_TOTAL))[t];
  }
  __syncthreads();
  for (int i = t; i < RC_ROWS * OUT_DIM; i += 256) {
    int mr = i / OUT_DIM;
    int o = i - mr * OUT_DIM;
    int mm = blockIdx.x * RC_ROWS + mr;
    int b = mm / V_DIM;
    const float* srow = sS + mr * N_TOTAL;
    float res = srow[o] + b_base[o];
    float moe = 0.0f;
    #pragma unroll
    for (int e = 0; e < E_DIM; ++e) {
      float we = wfull[b * E_DIM + e];
      if (we != 0.0f) {
        const float* lb = lora_B + ((size_t)e * OUT_DIM + o) * R_DIM;
        float dd = 0.0f;
        #pragma unroll
        for (int r = 0; r < R_DIM; ++r) dd += srow[OUT_DIM + e * R_DIM + r] * lb[r];
        moe += we * dd;
      }
    }
    out[(size_t)mm * OUT_DIM + o] = res + SCALING * moe;
  }
}

extern "C" void kernel_launch(void* const* d_in, const int* in_sizes, int n_in,
                              void* d_out, int out_size, void* d_ws, size_t ws_size,
                              hipStream_t stream) {
  const float* x      = (const float*)d_in[0];
  const float* W_base = (const float*)d_in[1];
  const float* b_base = (const float*)d_in[2];
  const float* W1     = (const float*)d_in[3];
  const float* b1     = (const float*)d_in[4];
  const float* W2     = (const float*)d_in[5];
  const float* b2     = (const float*)d_in[6];
  const float* lora_A = (const float*)d_in[7];
  const float* lora_B = (const float*)d_in[8];
  float* out = (float*)d_out;

  // ws layout: pooled[16384 f] | wfull[256 f] | S[107520 f] | Wb[160*32768 bf16]
  float* ws     = (float*)d_ws;
  float* pooled = ws;
  float* wfull  = ws + 16384;
  float* S      = wfull + 256;
  short* Wb     = (short*)(S + SMN);

  convW_kernel<<<(N_TOTAL * K_TOTAL / 8 + 255) / 256, 256, 0, stream>>>(
      W_base, lora_A, Wb, pooled, S);
  gemm_kernel<<<dim3(11, KSPLIT), 256, 0, stream>>>(x, Wb, S, pooled);
  router_kernel<<<B_DIM, 256, 0, stream>>>(pooled, W1, b1, W2, b2, wfull,
                                           out + (size_t)M_TOTAL * OUT_DIM);
  combine_kernel<<<M_TOTAL / RC_ROWS, 256, 0, stream>>>(
      S, b_base, lora_B, wfull, out);
}

// Round 13
// 204.179 us; speedup vs baseline: 1.0128x; 1.0128x over previous
//
#include <hip/hip_runtime.h>

// Problem constants
#define B_DIM 32
#define V_DIM 21
#define D_DIM 512
#define P_DIM 64
#define M_TOTAL 672          // B*V
#define K_TOTAL 32768        // D*P
#define OUT_DIM 96
#define E_DIM 8
#define R_DIM 8
#define H_DIM 256
#define N_TOTAL 160          // OUT_DIM + E*R
#define SCALING 2.0f
#define POOL_SCALE (1.0f / (V_DIM * (float)P_DIM))

// GEMM tiling: coalesced LDS staging, small tiles for residency.
#define BM 64
#define BK 64
#define KSPLIT 64
#define K_PER_SPLIT (K_TOTAL / KSPLIT)   // 512
#define CHUNKS (K_PER_SPLIT / BK)        // 8
#define LDS_K (BK + 8)                   // 72 shorts/row: row stride 144B -> 4-bank rotate
#define LDS_RED_S 20                     // pooled-scratch row stride (floats): 80B, 16B-aligned
#define SMN (M_TOTAL * N_TOTAL)          // 107520 per partial plane
#define RC_ROWS 4                        // rows per reduce_combine block

typedef __attribute__((ext_vector_type(4))) float floatx4;
typedef __attribute__((ext_vector_type(8))) short short8;
typedef __attribute__((ext_vector_type(4))) short shortx4;  // 'short4' is a HIP builtin

__device__ __forceinline__ unsigned short f2bf(float f) {
  union { float f; unsigned int u; } v; v.f = f;
  unsigned int u = v.u + (0x7FFFu + ((v.u >> 16) & 1u));  // RNE
  return (unsigned short)(u >> 16);
}

// ------- convW: [W_base|lora_A] fp32 -> bf16 Wb[160][32768]; also zero pooled
__global__ __launch_bounds__(256)
void convW_kernel(const float* __restrict__ W_base, const float* __restrict__ lora_A,
                  short* __restrict__ Wb, float* __restrict__ pooled) {
  int gid = blockIdx.x * 256 + threadIdx.x;
  if (blockIdx.x < 64) pooled[gid] = 0.0f;   // 16384 floats zeroed (grid is 2560 blocks)
  size_t base = (size_t)gid * 8;
  int row = (int)(base >> 15);
  int k = (int)(base & 32767);
  const float* src = (row < OUT_DIM) ? (W_base + ((size_t)row << 15) + k)
                                     : (lora_A + ((size_t)(row - OUT_DIM) << 15) + k);
  floatx4 v0 = ((const floatx4*)src)[0];
  floatx4 v1 = ((const floatx4*)src)[1];
  short8 sv;
  sv[0] = (short)f2bf(v0[0]); sv[1] = (short)f2bf(v0[1]);
  sv[2] = (short)f2bf(v0[2]); sv[3] = (short)f2bf(v0[3]);
  sv[4] = (short)f2bf(v1[0]); sv[5] = (short)f2bf(v1[1]);
  sv[6] = (short)f2bf(v1[2]); sv[7] = (short)f2bf(v1[3]);
  *(short8*)(Wb + base) = sv;
}

// ------- gemm: P[ky][m][n] = x-chunk @ Wb^T; A,B staged via LDS (coalesced);
// plain-store partials. Pooling v2: per-thread partials -> linear lds_red
// writes (published by the existing top-of-loop barrier), row-summed by 64
// threads in the compute phase. 4 blocks/CU resident.
__global__ __launch_bounds__(256, 4)
void gemm_kernel(const float* __restrict__ x, const short* __restrict__ Wb,
                 float* __restrict__ P, float* __restrict__ pooled) {
  __shared__ short ldsA[BM * LDS_K];      //  9,216 B
  __shared__ short ldsB[N_TOTAL * LDS_K]; // 23,040 B
  __shared__ float lds_pool[5 * 8];       // [b_local][d_local = chunk]
  __shared__ __attribute__((aligned(16))) float lds_red[BM * LDS_RED_S]; // 5,120 B
  const int tid = threadIdx.x;
  const int m0 = blockIdx.x * BM;
  const int ky = blockIdx.y;
  const int kbase = ky * K_PER_SPLIT;
  const int lane = tid & 63;
  const int wave = tid >> 6;
  const int quad = lane >> 4;
  const int l16 = lane & 15;
  const int b_first = m0 / V_DIM;
  const int d_first = kbase >> 6;         // k = d*64 + p; one chunk == one d

  if (tid < 40) lds_pool[tid] = 0.0f;

  floatx4 acc[10];                        // wave: rows [wave*16,+16), all 160 n
  #pragma unroll
  for (int nt = 0; nt < 10; ++nt) acc[nt] = (floatx4)(0.0f);

  // staging coords: A: idx=it*256+tid -> arow=idx>>4, u=idx&15 (float4 units;
  // 16-thread group = one row = one d). B: brow=idx>>3, g=idx&7 (short8 units).
  floatx4 pa[4];
  short8 pb[5];

#define ISSUE(c)                                                                \
  {                                                                             \
    const int kc = kbase + (c) * BK;                                            \
    _Pragma("unroll")                                                           \
    for (int it = 0; it < 4; ++it) {                                            \
      int idx = it * 256 + tid;                                                 \
      int arow = idx >> 4;                                                      \
      int u = idx & 15;                                                         \
      int m = m0 + arow;                                                        \
      pa[it] = (m < M_TOTAL)                                                    \
          ? *(const floatx4*)(x + (size_t)m * K_TOTAL + kc + u * 4)             \
          : (floatx4)(0.0f);                                                    \
    }                                                                           \
    _Pragma("unroll")                                                           \
    for (int it = 0; it < 5; ++it) {                                            \
      int idx = it * 256 + tid;                                                 \
      int brow = idx >> 3;                                                      \
      int g = idx & 7;                                                          \
      pb[it] = *(const short8*)(Wb + (size_t)brow * K_TOTAL + kc + g * 8);      \
    }                                                                           \
  }

#define CONVERT_WRITE(c)                                                        \
  {                                                                             \
    _Pragma("unroll")                                                           \
    for (int it = 0; it < 4; ++it) {                                            \
      int idx = it * 256 + tid;                                                 \
      int arow = idx >> 4;                                                      \
      int u = idx & 15;                                                         \
      floatx4 v = pa[it];                                                       \
      /* pooling partial: one scalar per (row, u-slot); linear, conflict-free */\
      lds_red[arow * LDS_RED_S + u] = (v[0] + v[1]) + (v[2] + v[3]);            \
      shortx4 sv;                                                               \
      sv[0] = (short)f2bf(v[0]); sv[1] = (short)f2bf(v[1]);                     \
      sv[2] = (short)f2bf(v[2]); sv[3] = (short)f2bf(v[3]);                     \
      *(shortx4*)&ldsA[arow * LDS_K + u * 4] = sv;                              \
    }                                                                           \
    _Pragma("unroll")                                                           \
    for (int it = 0; it < 5; ++it) {                                            \
      int idx = it * 256 + tid;                                                 \
      int brow = idx >> 3;                                                      \
      int g = idx & 7;                                                          \
      *(short8*)&ldsB[brow * LDS_K + g * 8] = pb[it];                           \
    }                                                                           \
  }

  ISSUE(0);
  __syncthreads();          // lds_pool zeros visible before first atomicAdd
  CONVERT_WRITE(0);

  for (int c = 0; c < CHUNKS; ++c) {
    __syncthreads();        // LDS tiles + lds_red for chunk c ready
    if (c + 1 < CHUNKS) ISSUE(c + 1);     // next chunk's loads fly under MFMA
    #pragma unroll
    for (int ks = 0; ks < 2; ++ks) {
      const int ko = ks * 32 + quad * 8;
      short8 a = *(const short8*)&ldsA[(wave * 16 + l16) * LDS_K + ko];
      #pragma unroll
      for (int nt = 0; nt < 10; ++nt) {
        short8 b = *(const short8*)&ldsB[(nt * 16 + l16) * LDS_K + ko];
        acc[nt] = __builtin_amdgcn_mfma_f32_16x16x32_bf16(a, b, acc[nt], 0, 0, 0);
      }
    }
    // row-sum of lds_red (chunk c = d_first + c): 64 threads, 16 per wave.
    // Reads complete before the bottom barrier; lds_red overwritten only
    // after it (CONVERT_WRITE(c+1)).
    if (quad == 0) {
      int r = wave * 16 + l16;
      const floatx4* rr = (const floatx4*)&lds_red[r * LDS_RED_S];
      floatx4 t0 = rr[0], t1 = rr[1], t2 = rr[2], t3 = rr[3];
      floatx4 tt = (t0 + t1) + (t2 + t3);
      float s = (tt[0] + tt[1]) + (tt[2] + tt[3]);
      int m = m0 + r;
      if (m < M_TOTAL)
        atomicAdd(&lds_pool[(m / V_DIM - b_first) * 8 + c], s);
    }
    __syncthreads();        // all LDS reads of chunk c done
    if (c + 1 < CHUNKS) CONVERT_WRITE(c + 1);
  }

  // partial-plane store (D layout: col=lane&15, row=quad*4+reg) — plain stores
  {
    const int mrow = m0 + wave * 16 + quad * 4;
    float* Pp = P + (size_t)ky * SMN + (size_t)mrow * N_TOTAL + l16;
    #pragma unroll
    for (int r = 0; r < 4; ++r)
      if (mrow + r < M_TOTAL)
        #pragma unroll
        for (int nt = 0; nt < 10; ++nt)
          Pp[(size_t)r * N_TOTAL + nt * 16] = acc[nt][r];
  }

  // pooled partials -> global (40 atomics/block); ordered by the loop's final
  // bottom barrier.
  if (tid < 40) {
    int b = b_first + (tid >> 3);
    int d = d_first + (tid & 7);
    if (b < B_DIM)
      atomicAdd(&pooled[b * D_DIM + d], lds_pool[tid] * POOL_SCALE);
  }
}

// ---------------- router: MLP + softmax + top-2 ------------------------------
__global__ __launch_bounds__(256)
void router_kernel(const float* __restrict__ pooled, const float* __restrict__ W1,
                   const float* __restrict__ b1, const float* __restrict__ W2,
                   const float* __restrict__ b2, float* __restrict__ wfull,
                   float* __restrict__ probs_out) {
  __shared__ float sp[D_DIM];
  __shared__ float sh[H_DIM];
  __shared__ float slog[E_DIM];
  const int b = blockIdx.x;
  const int t = threadIdx.x;
  sp[t] = pooled[b * D_DIM + t];
  sp[t + 256] = pooled[b * D_DIM + t + 256];
  __syncthreads();
  float acc = b1[t];
  const float* w1r = W1 + (size_t)t * D_DIM;
  for (int d = 0; d < D_DIM; ++d) acc += sp[d] * w1r[d];
  sh[t] = fmaxf(acc, 0.0f);
  __syncthreads();
  if (t < E_DIM) {
    float a = b2[t];
    const float* w2r = W2 + t * H_DIM;
    for (int j = 0; j < H_DIM; ++j) a += sh[j] * w2r[j];
    slog[t] = a;
  }
  __syncthreads();
  if (t == 0) {
    float p[E_DIM];
    float mx = slog[0];
    for (int e = 1; e < E_DIM; ++e) mx = fmaxf(mx, slog[e]);
    float se = 0.0f;
    for (int e = 0; e < E_DIM; ++e) { p[e] = __expf(slog[e] - mx); se += p[e]; }
    float inv = 1.0f / se;
    for (int e = 0; e < E_DIM; ++e) { p[e] *= inv; probs_out[b * E_DIM + e] = p[e]; }
    // top-2, lowest index wins ties (strict > keeps earlier index)
    int i0 = 0;
    for (int e = 1; e < E_DIM; ++e) if (p[e] > p[i0]) i0 = e;
    int i1 = (i0 == 0) ? 1 : 0;
    for (int e = 0; e < E_DIM; ++e) if (e != i0 && p[e] > p[i1]) i1 = e;
    float s2 = p[i0] + p[i1];
    float invs = 1.0f / fmaxf(s2, 1e-6f);
    for (int e = 0; e < E_DIM; ++e) {
      float w = 0.0f;
      if (e == i0) w += p[i0] * invs;
      if (e == i1) w += p[i1] * invs;
      wfull[b * E_DIM + e] = w;
    }
  }
}

// ------- reduce partials over KSPLIT + combine: out = S_b + b_base + 2*Σ w·(S_l·B)
// float4 P loads (4x in-flight bytes), RC_ROWS=4 -> 168 blocks.
__global__ __launch_bounds__(256)
void reduce_combine_kernel(const float* __restrict__ P, const float* __restrict__ b_base,
                           const float* __restrict__ lora_B, const float* __restrict__ wfull,
                           float* __restrict__ out) {
  __shared__ float sS[RC_ROWS * N_TOTAL];   // 640 floats
  const int t = threadIdx.x;
  const int NF4 = RC_ROWS * N_TOTAL / 4;    // 160 float4 per block
  if (t < NF4) {
    const floatx4* P4 = (const floatx4*)P;
    size_t base = (size_t)blockIdx.x * NF4 + t;
    floatx4 a = (floatx4)(0.0f);
    #pragma unroll 8
    for (int k = 0; k < KSPLIT; ++k) a += P4[(size_t)k * (SMN / 4) + base];
    *(floatx4*)&sS[t * 4] = a;
  }
  __syncthreads();
  for (int i = t; i < RC_ROWS * OUT_DIM; i += 256) {
    int mr = i / OUT_DIM;
    int o = i - mr * OUT_DIM;
    int mm = blockIdx.x * RC_ROWS + mr;
    int b = mm / V_DIM;
    const float* srow = sS + mr * N_TOTAL;
    float res = srow[o] + b_base[o];
    float moe = 0.0f;
    #pragma unroll
    for (int e = 0; e < E_DIM; ++e) {
      float we = wfull[b * E_DIM + e];
      if (we != 0.0f) {
        const float* lb = lora_B + ((size_t)e * OUT_DIM + o) * R_DIM;
        float dd = 0.0f;
        #pragma unroll
        for (int r = 0; r < R_DIM; ++r) dd += srow[OUT_DIM + e * R_DIM + r] * lb[r];
        moe += we * dd;
      }
    }
    out[(size_t)mm * OUT_DIM + o] = res + SCALING * moe;
  }
}

extern "C" void kernel_launch(void* const* d_in, const int* in_sizes, int n_in,
                              void* d_out, int out_size, void* d_ws, size_t ws_size,
                              hipStream_t stream) {
  const float* x      = (const float*)d_in[0];
  const float* W_base = (const float*)d_in[1];
  const float* b_base = (const float*)d_in[2];
  const float* W1     = (const float*)d_in[3];
  const float* b1     = (const float*)d_in[4];
  const float* W2     = (const float*)d_in[5];
  const float* b2     = (const float*)d_in[6];
  const float* lora_A = (const float*)d_in[7];
  const float* lora_B = (const float*)d_in[8];
  float* out = (float*)d_out;

  // ws layout: pooled[16384 f] | wfull[256 f] | Wb[160*32768 bf16] | P[64*107520 f]
  float* ws     = (float*)d_ws;
  float* pooled = ws;
  float* wfull  = ws + 16384;
  short* Wb     = (short*)(wfull + 256);
  float* P      = (float*)(Wb + (size_t)N_TOTAL * K_TOTAL);

  convW_kernel<<<(N_TOTAL * K_TOTAL / 8 + 255) / 256, 256, 0, stream>>>(
      W_base, lora_A, Wb, pooled);
  gemm_kernel<<<dim3(11, KSPLIT), 256, 0, stream>>>(x, Wb, P, pooled);
  router_kernel<<<B_DIM, 256, 0, stream>>>(pooled, W1, b1, W2, b2, wfull,
                                           out + (size_t)M_TOTAL * OUT_DIM);
  reduce_combine_kernel<<<M_TOTAL / RC_ROWS, 256, 0, stream>>>(
      P, b_base, lora_B, wfull, out);
}